// Round 6
// baseline (197.587 us; speedup 1.0000x reference)
//
#include <hip/hip_runtime.h>

#define B_ 8
#define N_ 4096
#define C_ 768
#define NP_ 4095
#define H_ 16
#define D_ 48
#define HID_ 3072
#define SCALE 0.14433756729740643f  // 1/sqrt(48)

// -------- k_copy: out = x, pure f32 copy, float4 grid-stride -----------------
__global__ __launch_bounds__(256) void k_copy(const float* __restrict__ x,
    float* __restrict__ outp)
{
  const size_t n4 = (size_t)B_*N_*C_/4;   // 6291456 float4s
  size_t i = (size_t)blockIdx.x*blockDim.x + threadIdx.x;
  size_t stride = (size_t)gridDim.x*blockDim.x;
  const float4* xv = (const float4*)x;
  float4* ov = (float4*)outp;
  for (size_t e = i; e < n4; e += stride) ov[e] = xv[e];
}

// ---------------- k_ln_last: xnlast[b] = LN(x[b, 4095, :]) -------------------
__global__ __launch_bounds__(256) void k_ln_last(const float* __restrict__ x,
    float* __restrict__ xnlast)
{
  int b = blockIdx.x, t = threadIdx.x;
  __shared__ float redA[4], redB[4];
  const float* xr = x + ((size_t)b*N_ + NP_)*C_;
  float v0 = xr[t], v1 = xr[t+256], v2 = xr[t+512];
  float s = v0+v1+v2, q = v0*v0+v1*v1+v2*v2;
  #pragma unroll
  for (int off=32; off; off>>=1){ s += __shfl_xor(s,off); q += __shfl_xor(q,off); }
  int w = t>>6, l = t&63;
  if (l==0){ redA[w]=s; redB[w]=q; }
  __syncthreads();
  s = redA[0]+redA[1]+redA[2]+redA[3];
  q = redB[0]+redB[1]+redB[2]+redB[3];
  float mean = s*(1.f/C_), var = q*(1.f/C_) - mean*mean;
  float rstd = rsqrtf(var + 1e-6f);
  float* o = xnlast + (size_t)b*C_;
  o[t] = (v0-mean)*rstd; o[t+256] = (v1-mean)*rstd; o[t+512] = (v2-mean)*rstd;
}

// ---------------- k_q: qv[b,j] = xnlast[b] @ Wq[:,j] + bq[j] -----------------
__global__ __launch_bounds__(256) void k_q(const float* __restrict__ xnlast,
    const float* __restrict__ Wq, const float* __restrict__ bq,
    float* __restrict__ qv)
{
  int b = blockIdx.y, t = threadIdx.x;
  int j0 = blockIdx.x*32;
  __shared__ float xs[C_];
  __shared__ float red[32][9];
  for (int u=t; u<C_; u+=256) xs[u] = xnlast[(size_t)b*C_+u];
  __syncthreads();
  int jl = t&31, part = t>>5;
  const float* wp = Wq + (size_t)(part*96)*C_ + j0 + jl;
  const float* xp = xs + part*96;
  float acc = 0.f;
  #pragma unroll 8
  for (int c=0;c<96;c++) acc += xp[c]*wp[(size_t)c*C_];
  red[jl][part] = acc;
  __syncthreads();
  if (part==0){
    float a = bq[j0+jl];
    #pragma unroll
    for (int p=0;p<8;p++) a += red[jl][p];
    qv[(size_t)b*C_ + j0 + jl] = a;
  }
}

// --------- k_qw: qWf[b,h,c] = sum_d qv[b,h*48+d]*Wkv[c, h*48+d]  (f32) -------
__global__ __launch_bounds__(256) void k_qw(const float* __restrict__ qv,
    const float* __restrict__ Wkv, float* __restrict__ qWf)
{
  int b = blockIdx.y, t = threadIdx.x;
  int c0 = blockIdx.x*16;
  __shared__ float qs[C_];
  for (int u=t; u<C_; u+=256) qs[u] = qv[(size_t)b*C_+u];
  __syncthreads();
  int h = t&15, cl = t>>4;
  int c = c0 + cl;
  const float* wp = Wkv + (size_t)c*(2*C_) + h*D_;
  const float* qh = qs + h*D_;
  float acc = 0.f;
  #pragma unroll
  for (int d=0; d<D_; d++) acc += qh[d]*wp[d];
  qWf[((size_t)b*H_ + h)*C_ + c] = acc;
}

// ---- k_attn: row LN stats; sim via VALU dots; w=exp(sim*SCALE);          ----
// ----         ctx[b,h,c] += sum_k w*xn[k,c]; denom[b,h] += sum_k w        ----
__global__ __launch_bounds__(256) void k_attn(const float* __restrict__ x,
    const float* __restrict__ qWf, float* __restrict__ ctx,
    float* __restrict__ denom)
{
  int b = blockIdx.y;
  int w = threadIdx.x>>6, l = threadIdx.x&63;
  int kblk = blockIdx.x*64;
  int base = kblk + w*16;
  __shared__ float qlds[H_][772];    // padded to kill bank conflicts
  __shared__ float qwsum[H_];
  __shared__ float pt[16][17];
  __shared__ float wexp[64][H_];
  __shared__ float2 stl[64];
  const size_t xb = (size_t)b*N_*C_;

  // stage qW -> LDS
  for (int h=0; h<H_; ++h)
    for (int c=threadIdx.x; c<C_; c+=256)
      qlds[h][c] = qWf[((size_t)b*H_ + h)*C_ + c];
  __syncthreads();
  // per-head column sums (for LN-mean folding)
  {
    int th = threadIdx.x>>4, tl = threadIdx.x&15;
    float ps = 0.f;
    #pragma unroll 8
    for (int j=0;j<48;j++) ps += qlds[th][tl*48+j];
    pt[th][tl] = ps;
  }
  __syncthreads();
  if (threadIdx.x < H_){
    float s = 0.f;
    #pragma unroll
    for (int j=0;j<16;j++) s += pt[threadIdx.x][j];
    qwsum[threadIdx.x] = s;
  }
  // per-row LN stats (wave w: rows base..base+15)
  for (int i=0;i<16;i++){
    int kt = base + i;
    int ktc = kt < NP_ ? kt : (NP_-1);
    const float4* rp = (const float4*)(x + xb + (size_t)ktc*C_);
    float4 f0 = rp[l], f1 = rp[l+64], f2 = rp[l+128];
    float s = f0.x+f0.y+f0.z+f0.w + f1.x+f1.y+f1.z+f1.w + f2.x+f2.y+f2.z+f2.w;
    float q = f0.x*f0.x+f0.y*f0.y+f0.z*f0.z+f0.w*f0.w
            + f1.x*f1.x+f1.y*f1.y+f1.z*f1.z+f1.w*f1.w
            + f2.x*f2.x+f2.y*f2.y+f2.z*f2.z+f2.w*f2.w;
    #pragma unroll
    for (int off=32; off; off>>=1){ s += __shfl_xor(s,off); q += __shfl_xor(q,off); }
    float mean = s*(1.f/C_), var = q*(1.f/C_) - mean*mean;
    float rstd = rsqrtf(var + 1e-6f);
    if (l==0) stl[w*16+i] = make_float2(mean, rstd);
  }
  __syncthreads();

  // sim: lane = (head hh = l&15, quarter qq = l>>4); sim = rs*(x.qW - mu*sum(qW))
  {
    int hh = l&15, qq = l>>4;
    const float* qrow = &qlds[hh][qq*192];
    for (int i=0;i<16;i++){
      int kt = base + i;
      int ktc = kt < NP_ ? kt : (NP_-1);
      const float4* xr = (const float4*)(x + xb + (size_t)ktc*C_ + qq*192);
      float acc = 0.f;
      #pragma unroll 12
      for (int j=0;j<48;j++){
        float4 xv = xr[j];
        float4 qv4 = *(const float4*)(qrow + j*4);
        acc += xv.x*qv4.x + xv.y*qv4.y + xv.z*qv4.z + xv.w*qv4.w;
      }
      acc += __shfl_xor(acc, 16);
      acc += __shfl_xor(acc, 32);
      if (qq == 0){
        float2 ms = stl[w*16+i];
        float simv = ms.y * (acc - ms.x*qwsum[hh]);
        float wv = (kt < NP_) ? __expf(simv*SCALE) : 0.f;
        wexp[w*16+i][hh] = wv;
      }
    }
  }
  __syncthreads();

  // denom
  if (threadIdx.x < H_){
    float s = 0.f;
    #pragma unroll 8
    for (int k=0;k<64;k++) s += wexp[k][threadIdx.x];
    atomicAdd(denom + (size_t)b*H_ + threadIdx.x, s);
  }
  // ctx partials: wave w owns columns [w*192, w*192+192)
  int c0 = w*192;
  float accc[H_][3];
  #pragma unroll
  for (int h=0;h<H_;h++){ accc[h][0]=0.f; accc[h][1]=0.f; accc[h][2]=0.f; }
  for (int k=0;k<64;k++){
    int kt = kblk + k;
    int ktc = kt < NP_ ? kt : (NP_-1);
    const float* xr = x + xb + (size_t)ktc*C_ + c0;
    float2 ms = stl[k];
    float x0 = (xr[l]     - ms.x)*ms.y;
    float x1 = (xr[l+64]  - ms.x)*ms.y;
    float x2 = (xr[l+128] - ms.x)*ms.y;
    #pragma unroll
    for (int h=0;h<H_;h++){
      float a = wexp[k][h];
      accc[h][0] += a*x0; accc[h][1] += a*x1; accc[h][2] += a*x2;
    }
  }
  float* cb = ctx + (size_t)b*H_*C_;
  #pragma unroll
  for (int h=0;h<H_;h++){
    atomicAdd(cb + h*C_ + c0 + l,       accc[h][0]);
    atomicAdd(cb + h*C_ + c0 + 64 + l,  accc[h][1]);
    atomicAdd(cb + h*C_ + c0 + 128 + l, accc[h][2]);
  }
}

// ------ k_v: oat[b,t] = (ctx[b,h(t),:]/denom[b,h(t)]) @ Wv[:,t] + bv[t] ------
__global__ __launch_bounds__(256) void k_v(const float* __restrict__ ctx,
    const float* __restrict__ denom, const float* __restrict__ Wkv,
    const float* __restrict__ bkv, float* __restrict__ oat)
{
  int b = blockIdx.y, t = threadIdx.x;
  int t0 = blockIdx.x*32;
  int h0 = t0/D_;
  int h1 = (t0+31)/D_; if (h1 > H_-1) h1 = H_-1;
  __shared__ float cn[2][C_];
  __shared__ float red[32][9];
  float inv0 = 1.f/denom[(size_t)b*H_+h0];
  float inv1 = 1.f/denom[(size_t)b*H_+h1];
  for (int u=t; u<C_; u+=256){
    cn[0][u] = ctx[((size_t)b*H_+h0)*C_+u]*inv0;
    cn[1][u] = ctx[((size_t)b*H_+h1)*C_+u]*inv1;
  }
  __syncthreads();
  int jl = t&31, part = t>>5;
  int tt = t0 + jl;
  int hi = (tt/D_) - h0;   // 0 or 1
  const float* wp = Wkv + (size_t)(part*96)*(2*C_) + C_ + tt;
  const float* cp = cn[hi] + part*96;
  float acc = 0.f;
  #pragma unroll 8
  for (int c=0;c<96;c++) acc += cp[c]*wp[(size_t)c*(2*C_)];
  red[jl][part] = acc;
  __syncthreads();
  if (part==0){
    float a = bkv[C_ + tt];
    #pragma unroll
    for (int p=0;p<8;p++) a += red[jl][p];
    oat[(size_t)b*C_ + tt] = a;
  }
}

// ------- k_o: lastb[b,t] = x[b,4095,t] + oat[b] @ Wo[:,t] + bo[t] ------------
__global__ __launch_bounds__(256) void k_o(const float* __restrict__ x,
    const float* __restrict__ oat, const float* __restrict__ Wo,
    const float* __restrict__ bo, float* __restrict__ lastb)
{
  int b = blockIdx.y, t = threadIdx.x;
  int t0 = blockIdx.x*32;
  __shared__ float xs[C_];
  __shared__ float red[32][9];
  for (int u=t; u<C_; u+=256) xs[u] = oat[(size_t)b*C_+u];
  __syncthreads();
  int jl = t&31, part = t>>5;
  int tt = t0 + jl;
  const float* wp = Wo + (size_t)(part*96)*C_ + tt;
  const float* xp = xs + part*96;
  float acc = 0.f;
  #pragma unroll 8
  for (int c=0;c<96;c++) acc += xp[c]*wp[(size_t)c*C_];
  red[jl][part] = acc;
  __syncthreads();
  if (part==0){
    float a = bo[tt];
    #pragma unroll
    for (int p=0;p<8;p++) a += red[jl][p];
    lastb[(size_t)b*C_ + tt] = x[((size_t)b*N_ + NP_)*C_ + tt] + a;
  }
}

// ---------------- k_ln2: ln2[b] = LN(lastb[b]) -------------------------------
__global__ __launch_bounds__(256) void k_ln2(const float* __restrict__ lastb,
    float* __restrict__ ln2)
{
  int b = blockIdx.x, t = threadIdx.x;
  __shared__ float redA[4], redB[4];
  const float* xr = lastb + (size_t)b*C_;
  float v0 = xr[t], v1 = xr[t+256], v2 = xr[t+512];
  float s = v0+v1+v2, q = v0*v0+v1*v1+v2*v2;
  #pragma unroll
  for (int off=32; off; off>>=1){ s += __shfl_xor(s,off); q += __shfl_xor(q,off); }
  int w = t>>6, l = t&63;
  if (l==0){ redA[w]=s; redB[w]=q; }
  __syncthreads();
  s = redA[0]+redA[1]+redA[2]+redA[3];
  q = redB[0]+redB[1]+redB[2]+redB[3];
  float mean = s*(1.f/C_), var = q*(1.f/C_) - mean*mean;
  float rstd = rsqrtf(var + 1e-6f);
  float* o = ln2 + (size_t)b*C_;
  o[t] = (v0-mean)*rstd; o[t+256] = (v1-mean)*rstd; o[t+512] = (v2-mean)*rstd;
}

// ---------------- k_mlp1: hid = gelu(ln2 @ W1 + b1) --------------------------
__global__ __launch_bounds__(256) void k_mlp1(const float* __restrict__ ln2,
    const float* __restrict__ W1, const float* __restrict__ b1,
    float* __restrict__ hid)
{
  int b = blockIdx.y, t = threadIdx.x;
  int j0 = blockIdx.x*64;
  __shared__ float xs[C_];
  __shared__ float red[64][5];
  for (int u=t; u<C_; u+=256) xs[u] = ln2[(size_t)b*C_+u];
  __syncthreads();
  int jl = t&63, part = t>>6;
  const float* wp = W1 + (size_t)(part*192)*HID_ + j0 + jl;
  const float* xp = xs + part*192;
  float acc = 0.f;
  #pragma unroll 8
  for (int c=0;c<192;c++) acc += xp[c]*wp[(size_t)c*HID_];
  red[jl][part] = acc;
  __syncthreads();
  if (part==0){
    float a = b1[j0+jl];
    #pragma unroll
    for (int p=0;p<4;p++) a += red[jl][p];
    float t3 = a + 0.044715f*a*a*a;
    float g = 0.5f*a*(1.f + tanhf(0.7978845608f*t3));
    hid[(size_t)b*HID_ + j0 + jl] = g;
  }
}

// ------- k_mlp2: out row 4095 = lastb + hid @ W2 + b2  (f32 store) -----------
__global__ __launch_bounds__(256) void k_mlp2(const float* __restrict__ hid,
    const float* __restrict__ W2, const float* __restrict__ b2,
    const float* __restrict__ lastb, float* __restrict__ outp)
{
  int b = blockIdx.y, t = threadIdx.x;
  int c0 = blockIdx.x*16;
  __shared__ float hs[HID_];
  __shared__ float red[16][17];
  for (int u=t; u<HID_; u+=256) hs[u] = hid[(size_t)b*HID_+u];
  __syncthreads();
  int ccl = t&15, part = t>>4;
  int cc = c0 + ccl;
  const float* wp = W2 + (size_t)(part*192)*C_ + cc;
  const float* hp = hs + part*192;
  float acc = 0.f;
  #pragma unroll 8
  for (int j=0;j<192;j++) acc += hp[j]*wp[(size_t)j*C_];
  red[ccl][part] = acc;
  __syncthreads();
  if (part==0){
    float a = b2[cc] + lastb[(size_t)b*C_ + cc];
    #pragma unroll
    for (int p=0;p<16;p++) a += red[ccl][p];
    outp[((size_t)b*N_ + NP_)*C_ + cc] = a;
  }
}

extern "C" void kernel_launch(void* const* d_in, const int* in_sizes, int n_in,
                              void* d_out, int out_size, void* d_ws, size_t ws_size,
                              hipStream_t stream)
{
  (void)in_sizes; (void)n_in; (void)out_size; (void)ws_size;
  const float* x   = (const float*)d_in[0];
  const float* Wq  = (const float*)d_in[1];
  const float* bq  = (const float*)d_in[2];
  const float* Wkv = (const float*)d_in[3];
  const float* bkv = (const float*)d_in[4];
  const float* Wo  = (const float*)d_in[5];
  const float* bo  = (const float*)d_in[6];
  const float* W1  = (const float*)d_in[7];
  const float* b1  = (const float*)d_in[8];
  const float* W2  = (const float*)d_in[9];
  const float* b2  = (const float*)d_in[10];
  float* outp = (float*)d_out;
  float* ws = (float*)d_ws;
  // ws layout (f32 units), total ~246K f32 = 984 KB
  float* ctx    = ws;                  // [8][16][768] = 98304
  float* denom  = ctx + 98304;         // [8][16]      = 128
  float* xnlast = denom + 128;         // [8][768]     = 6144
  float* qv     = xnlast + 6144;       // [8][768]     = 6144
  float* oat    = qv + 6144;           // [8][768]     = 6144
  float* lastb  = oat + 6144;          // [8][768]     = 6144
  float* ln2    = lastb + 6144;        // [8][768]     = 6144
  float* hid    = ln2 + 6144;          // [8][3072]    = 24576
  float* qWf    = hid + 24576;         // [8][16][768] = 98304

  hipMemsetAsync(ctx, 0, (size_t)(98304+128)*sizeof(float), stream);
  hipLaunchKernelGGL(k_copy, dim3(2048), dim3(256), 0, stream, x, outp);
  hipLaunchKernelGGL(k_ln_last, dim3(B_), dim3(256), 0, stream, x, xnlast);
  hipLaunchKernelGGL(k_q,    dim3(24,B_), dim3(256), 0, stream, xnlast, Wq, bq, qv);
  hipLaunchKernelGGL(k_qw,   dim3(48,B_), dim3(256), 0, stream, qv, Wkv, qWf);
  hipLaunchKernelGGL(k_attn, dim3(64,B_), dim3(256), 0, stream, x, qWf, ctx, denom);
  hipLaunchKernelGGL(k_v,    dim3(24,B_), dim3(256), 0, stream, ctx, denom, Wkv, bkv, oat);
  hipLaunchKernelGGL(k_o,    dim3(24,B_), dim3(256), 0, stream, x, oat, Wo, bo, lastb);
  hipLaunchKernelGGL(k_ln2,  dim3(B_), dim3(256), 0, stream, lastb, ln2);
  hipLaunchKernelGGL(k_mlp1, dim3(48,B_), dim3(256), 0, stream, ln2, W1, b1, hid);
  hipLaunchKernelGGL(k_mlp2, dim3(48,B_), dim3(256), 0, stream, hid, W2, b2, lastb, outp);
}

// Round 7
// 123.288 us; speedup vs baseline: 1.6027x; 1.6027x over previous
//
#include <hip/hip_runtime.h>

#define B_ 8
#define N_ 4096
#define C_ 768
#define NP_ 4095
#define H_ 16
#define D_ 48
#define HID_ 3072
#define SCALE 0.14433756729740643f  // 1/sqrt(48)

typedef unsigned short u16;
typedef unsigned int u32;
typedef __attribute__((ext_vector_type(4))) float f32x4;
typedef __attribute__((ext_vector_type(8))) short short8;

__device__ __forceinline__ u32 f2bf_bits(float f){
  union { float f; u32 i; } v; v.f = f;
  return (v.i + 0x7fffu + ((v.i >> 16) & 1u)) >> 16;
}
__device__ __forceinline__ u32 pack2(float a, float b){
  return f2bf_bits(a) | (f2bf_bits(b) << 16);
}
__device__ __forceinline__ float bf2f(u16 u){
  union { u32 i; float f; } v; v.i = ((u32)u) << 16; return v.f;
}
__device__ __forceinline__ float2 up2(u32 u){
  union { u32 i; float f; } lo, hi;
  lo.i = u << 16; hi.i = u & 0xffff0000u;
  return make_float2(lo.f, hi.f);
}

// ---------------- k_q: qv[b,j] = LN(x[b,4095]) @ Wq[:,j] + bq[j] -------------
__global__ __launch_bounds__(256) void k_q(const float* __restrict__ x,
    const float* __restrict__ Wq, const float* __restrict__ bq,
    float* __restrict__ qv)
{
  int b = blockIdx.y, t = threadIdx.x;
  int j0 = blockIdx.x*32;
  __shared__ float xs[C_];
  __shared__ float red[32][9];
  __shared__ float redA[4], redB[4];
  // fused LN of last row
  const float* xr = x + ((size_t)b*N_ + NP_)*C_;
  float v0 = xr[t], v1 = xr[t+256], v2 = xr[t+512];
  float s = v0+v1+v2, q = v0*v0+v1*v1+v2*v2;
  #pragma unroll
  for (int off=32; off; off>>=1){ s += __shfl_xor(s,off); q += __shfl_xor(q,off); }
  int w = t>>6, l = t&63;
  if (l==0){ redA[w]=s; redB[w]=q; }
  __syncthreads();
  s = redA[0]+redA[1]+redA[2]+redA[3];
  q = redB[0]+redB[1]+redB[2]+redB[3];
  float mean = s*(1.f/C_), var = q*(1.f/C_) - mean*mean;
  float rstd = rsqrtf(var + 1e-6f);
  xs[t] = (v0-mean)*rstd; xs[t+256] = (v1-mean)*rstd; xs[t+512] = (v2-mean)*rstd;
  __syncthreads();
  int jl = t&31, part = t>>5;
  const float* wp = Wq + (size_t)(part*96)*C_ + j0 + jl;
  const float* xp = xs + part*96;
  float acc = 0.f;
  #pragma unroll 8
  for (int c=0;c<96;c++) acc += xp[c]*wp[(size_t)c*C_];
  red[jl][part] = acc;
  __syncthreads();
  if (part==0){
    float a = bq[j0+jl];
    #pragma unroll
    for (int p=0;p<8;p++) a += red[jl][p];
    qv[(size_t)b*C_ + j0 + jl] = a;
  }
}

// --------- k_qw: qWf[b,h,c] = sum_d qv[b,h*48+d]*Wkv[c, h*48+d]  (f32) -------
__global__ __launch_bounds__(256) void k_qw(const float* __restrict__ qv,
    const float* __restrict__ Wkv, float* __restrict__ qWf)
{
  int b = blockIdx.y, t = threadIdx.x;
  int c0 = blockIdx.x*16;
  __shared__ float qs[C_];
  for (int u=t; u<C_; u+=256) qs[u] = qv[(size_t)b*C_+u];
  __syncthreads();
  int h = t&15, cl = t>>4;
  int c = c0 + cl;
  const float* wp = Wkv + (size_t)c*(2*C_) + h*D_;
  const float* qh = qs + h*D_;
  float acc = 0.f;
  #pragma unroll
  for (int d=0; d<D_; d++) acc += qh[d]*wp[d];
  qWf[((size_t)b*H_ + h)*C_ + c] = acc;
}

// ---- k_attn: ONE x read: copy->out + LN stats + bf16 stage; MFMA sim;    ----
// ----         w=exp(); ctx from LDS tile; denom/S per head                ----
__global__ __launch_bounds__(512) void k_attn(const float* __restrict__ x,
    const float* __restrict__ qWf, float* __restrict__ outp,
    float* __restrict__ ctx, float* __restrict__ denom)
{
  int b = blockIdx.y;
  int tid = threadIdx.x;
  int w = tid>>6, l = tid&63;
  int kblk = blockIdx.x*64;
  __shared__ u32 xlds[64][388];     // 64 rows x 768 bf16 (+pad), 388%32==4
  __shared__ u32 qlds[16][388];     // 16 heads x 768 bf16
  __shared__ float walds[64][20];   // w*rs
  __shared__ float wexpl[64][20];   // w
  __shared__ float2 stl[64];
  __shared__ float pt[16][17];
  __shared__ float qwsum[16], sumS[16];
  const size_t xb = (size_t)b*N_*C_;

  // ---- stage x rows: copy + stats + bf16 pack (one global read) ----
  #pragma unroll
  for (int it=0; it<4; ++it){
    int r = it*16 + (tid>>5);
    int sub = tid & 31;
    int kt = kblk + r;
    const float4* rp = (const float4*)(x + xb + (size_t)kt*C_);
    float4* op = (float4*)(outp + xb + (size_t)kt*C_);
    float4 v[6];
    #pragma unroll
    for (int j=0;j<6;j++) v[j] = rp[sub + 32*j];
    float s=0.f, q=0.f;
    #pragma unroll
    for (int j=0;j<6;j++){
      op[sub + 32*j] = v[j];
      s += v[j].x+v[j].y+v[j].z+v[j].w;
      q += v[j].x*v[j].x + v[j].y*v[j].y + v[j].z*v[j].z + v[j].w*v[j].w;
      int ci = (sub + 32*j)*2;
      xlds[r][ci]   = pack2(v[j].x, v[j].y);
      xlds[r][ci+1] = pack2(v[j].z, v[j].w);
    }
    #pragma unroll
    for (int off=1; off<32; off<<=1){ s += __shfl_xor(s,off); q += __shfl_xor(q,off); }
    if (sub==0){
      float mean = s*(1.f/C_), var = q*(1.f/C_) - mean*mean;
      stl[r] = make_float2(mean, rsqrtf(var + 1e-6f));
    }
  }
  // ---- stage qW -> bf16 LDS ----
  for (int idx=tid; idx<H_*384; idx+=512){
    int h = idx/384, cu = idx - h*384;
    const float* qp = qWf + ((size_t)b*H_ + h)*C_ + cu*2;
    qlds[h][cu] = pack2(qp[0], qp[1]);
  }
  __syncthreads();
  // ---- qwsum[h] = sum_c qW_bf16[h][c] (consistent with MFMA dot) ----
  if (tid < 256){
    int th = tid>>4, tl = tid&15;
    float ps = 0.f;
    #pragma unroll
    for (int j=0;j<24;j++){ float2 p = up2(qlds[th][tl*24+j]); ps += p.x + p.y; }
    pt[th][tl] = ps;
  }
  __syncthreads();
  if (tid < 16){
    float s2 = 0.f;
    #pragma unroll
    for (int j=0;j<16;j++) s2 += pt[tid][j];
    qwsum[tid] = s2;
  }
  // ---- MFMA sim: wave w (<4) -> rows w*16..w*16+15, all 16 heads ----
  f32x4 acc = {0.f,0.f,0.f,0.f};
  if (w < 4){
    int arow = w*16 + (l&15);
    int ko = (l>>4)*4;
    #pragma unroll
    for (int s2=0;s2<24;s2++){
      union{uint4 u; short8 v;} A, Bf;
      A.u  = *(const uint4*)&xlds[arow][s2*16 + ko];
      Bf.u = *(const uint4*)&qlds[l&15][s2*16 + ko];
      acc = __builtin_amdgcn_mfma_f32_16x16x32_bf16(A.v, Bf.v, acc, 0,0,0);
    }
  }
  __syncthreads();   // qwsum ready for all waves
  if (w < 4){
    int hh = l&15, mb = (l>>4)*4;
    #pragma unroll
    for (int r=0;r<4;r++){
      int rr = w*16 + mb + r;
      int kt = kblk + rr;
      float2 ms = stl[rr];
      float simv = ms.y * (acc[r] - ms.x*qwsum[hh]);
      float wv = (kt < NP_) ? __expf(simv*SCALE) : 0.f;
      wexpl[rr][hh] = wv;
      walds[rr][hh] = wv * ms.y;
    }
  }
  __syncthreads();
  // ---- denom + S[h] ----
  if (tid < 16){
    float ds = 0.f, ss = 0.f;
    for (int k=0;k<64;k++){ ds += wexpl[k][tid]; ss += walds[k][tid]*stl[k].x; }
    atomicAdd(denom + (size_t)b*H_ + tid, ds);
    sumS[tid] = ss;
  }
  __syncthreads();
  // ---- ctx: 8 waves x 96 cols; ctx[h][c] += sum_k (w*rs)*x_raw - S[h] ----
  int c0 = w*96;
  int cA = c0 + l;
  int cB = c0 + 64 + (l & 31);
  float accA[H_], accB[H_];
  #pragma unroll
  for (int h=0;h<H_;h++){ accA[h]=0.f; accB[h]=0.f; }
  const u16* xl = (const u16*)xlds;   // row stride 776 u16
  for (int k=0;k<64;k++){
    float xA = bf2f(xl[k*776 + cA]);
    float xB = bf2f(xl[k*776 + cB]);
    const float4* wp4 = (const float4*)&walds[k][0];
    float4 w0 = wp4[0], w1 = wp4[1], w2 = wp4[2], w3 = wp4[3];
    accA[0]+=w0.x*xA; accA[1]+=w0.y*xA; accA[2]+=w0.z*xA; accA[3]+=w0.w*xA;
    accA[4]+=w1.x*xA; accA[5]+=w1.y*xA; accA[6]+=w1.z*xA; accA[7]+=w1.w*xA;
    accA[8]+=w2.x*xA; accA[9]+=w2.y*xA; accA[10]+=w2.z*xA; accA[11]+=w2.w*xA;
    accA[12]+=w3.x*xA; accA[13]+=w3.y*xA; accA[14]+=w3.z*xA; accA[15]+=w3.w*xA;
    accB[0]+=w0.x*xB; accB[1]+=w0.y*xB; accB[2]+=w0.z*xB; accB[3]+=w0.w*xB;
    accB[4]+=w1.x*xB; accB[5]+=w1.y*xB; accB[6]+=w1.z*xB; accB[7]+=w1.w*xB;
    accB[8]+=w2.x*xB; accB[9]+=w2.y*xB; accB[10]+=w2.z*xB; accB[11]+=w2.w*xB;
    accB[12]+=w3.x*xB; accB[13]+=w3.y*xB; accB[14]+=w3.z*xB; accB[15]+=w3.w*xB;
  }
  float* cb = ctx + (size_t)b*H_*C_;
  #pragma unroll
  for (int h=0;h<H_;h++) atomicAdd(cb + h*C_ + cA, accA[h] - sumS[h]);
  if (l < 32){
    #pragma unroll
    for (int h=0;h<H_;h++) atomicAdd(cb + h*C_ + cB, accB[h] - sumS[h]);
  }
}

// ------ k_v: oat[b,t] = (ctx[b,h(t),:]/denom[b,h(t)]) @ Wv[:,t] + bv[t] ------
__global__ __launch_bounds__(256) void k_v(const float* __restrict__ ctx,
    const float* __restrict__ denom, const float* __restrict__ Wkv,
    const float* __restrict__ bkv, float* __restrict__ oat)
{
  int b = blockIdx.y, t = threadIdx.x;
  int t0 = blockIdx.x*32;
  int h0 = t0/D_;
  int h1 = (t0+31)/D_; if (h1 > H_-1) h1 = H_-1;
  __shared__ float cn[2][C_];
  __shared__ float red[32][9];
  float inv0 = 1.f/denom[(size_t)b*H_+h0];
  float inv1 = 1.f/denom[(size_t)b*H_+h1];
  for (int u=t; u<C_; u+=256){
    cn[0][u] = ctx[((size_t)b*H_+h0)*C_+u]*inv0;
    cn[1][u] = ctx[((size_t)b*H_+h1)*C_+u]*inv1;
  }
  __syncthreads();
  int jl = t&31, part = t>>5;
  int tt = t0 + jl;
  int hi = (tt/D_) - h0;   // 0 or 1
  const float* wp = Wkv + (size_t)(part*96)*(2*C_) + C_ + tt;
  const float* cp = cn[hi] + part*96;
  float acc = 0.f;
  #pragma unroll 8
  for (int c=0;c<96;c++) acc += cp[c]*wp[(size_t)c*(2*C_)];
  red[jl][part] = acc;
  __syncthreads();
  if (part==0){
    float a = bkv[C_ + tt];
    #pragma unroll
    for (int p=0;p<8;p++) a += red[jl][p];
    oat[(size_t)b*C_ + tt] = a;
  }
}

// ------- k_o: lastb[b,t] = x[b,4095,t] + oat[b] @ Wo[:,t] + bo[t] ------------
__global__ __launch_bounds__(256) void k_o(const float* __restrict__ x,
    const float* __restrict__ oat, const float* __restrict__ Wo,
    const float* __restrict__ bo, float* __restrict__ lastb)
{
  int b = blockIdx.y, t = threadIdx.x;
  int t0 = blockIdx.x*32;
  __shared__ float xs[C_];
  __shared__ float red[32][9];
  for (int u=t; u<C_; u+=256) xs[u] = oat[(size_t)b*C_+u];
  __syncthreads();
  int jl = t&31, part = t>>5;
  int tt = t0 + jl;
  const float* wp = Wo + (size_t)(part*96)*C_ + tt;
  const float* xp = xs + part*96;
  float acc = 0.f;
  #pragma unroll 8
  for (int c=0;c<96;c++) acc += xp[c]*wp[(size_t)c*C_];
  red[jl][part] = acc;
  __syncthreads();
  if (part==0){
    float a = bo[tt];
    #pragma unroll
    for (int p=0;p<8;p++) a += red[jl][p];
    lastb[(size_t)b*C_ + tt] = x[((size_t)b*N_ + NP_)*C_ + tt] + a;
  }
}

// --- k_mlp1 (batched): hid[b] = gelu(LN(lastb[b]) @ W1 + b1), W1 read once ---
__global__ __launch_bounds__(256) void k_mlp1(const float* __restrict__ lastb,
    const float* __restrict__ W1, const float* __restrict__ b1,
    float* __restrict__ hid)
{
  int t = threadIdx.x;
  int j0 = blockIdx.x*16;
  __shared__ float xs[B_][C_];
  __shared__ float red[16][16][8];
  // fused LN of lastb for all 8 batches (32 threads per batch)
  {
    int bb = t>>5, sub = t&31;
    const float* xr = lastb + (size_t)bb*C_;
    float s=0.f, q=0.f;
    #pragma unroll
    for (int j=0;j<24;j++){ float v = xr[sub+32*j]; s += v; q += v*v; }
    #pragma unroll
    for (int off=1; off<32; off<<=1){ s += __shfl_xor(s,off); q += __shfl_xor(q,off); }
    float mean = s*(1.f/C_), var = q*(1.f/C_) - mean*mean;
    float rstd = rsqrtf(var + 1e-6f);
    #pragma unroll
    for (int j=0;j<24;j++){ xs[bb][sub+32*j] = (xr[sub+32*j]-mean)*rstd; }
  }
  __syncthreads();
  int jl = t&15, part = t>>4;
  const float* wp = W1 + (size_t)(part*48)*HID_ + j0 + jl;
  float acc[B_];
  #pragma unroll
  for (int bb=0;bb<B_;bb++) acc[bb]=0.f;
  for (int c=0;c<48;c++){
    float wv = wp[(size_t)c*HID_];
    int cc = part*48 + c;
    #pragma unroll
    for (int bb=0;bb<B_;bb++) acc[bb] += xs[bb][cc]*wv;
  }
  #pragma unroll
  for (int bb=0;bb<B_;bb++) red[jl][part][bb] = acc[bb];
  __syncthreads();
  if (t < 128){
    int jl2 = t&15, bb = t>>4;
    float a = b1[j0+jl2];
    #pragma unroll
    for (int p=0;p<16;p++) a += red[jl2][p][bb];
    float t3 = a + 0.044715f*a*a*a;
    float g = 0.5f*a*(1.f + tanhf(0.7978845608f*t3));
    hid[(size_t)bb*HID_ + j0 + jl2] = g;
  }
}

// --- k_mlp2 (batched): out[b,4095,:] = lastb[b] + hid[b] @ W2 + b2 -----------
__global__ __launch_bounds__(256) void k_mlp2(const float* __restrict__ hid,
    const float* __restrict__ W2, const float* __restrict__ b2,
    const float* __restrict__ lastb, float* __restrict__ outp)
{
  int t = threadIdx.x;
  int c0 = blockIdx.x*8;
  __shared__ float red[8][32][8];
  int ccl = t&7, part = t>>3;        // 32 parts x 96 j each
  const float* wp = W2 + (size_t)(part*96)*C_ + c0 + ccl;
  float acc[B_];
  #pragma unroll
  for (int bb=0;bb<B_;bb++) acc[bb]=0.f;
  for (int j=0;j<96;j++){
    float wv = wp[(size_t)j*C_];
    int jj = part*96 + j;
    #pragma unroll
    for (int bb=0;bb<B_;bb++) acc[bb] += hid[(size_t)bb*HID_ + jj]*wv;
  }
  #pragma unroll
  for (int bb=0;bb<B_;bb++) red[ccl][part][bb] = acc[bb];
  __syncthreads();
  if (t < 64){
    int cc2 = t&7, bb = t>>3;
    float a = 0.f;
    #pragma unroll
    for (int p=0;p<32;p++) a += red[cc2][p][bb];
    int cc = c0 + cc2;
    a += b2[cc] + lastb[(size_t)bb*C_ + cc];
    outp[((size_t)bb*N_ + NP_)*C_ + cc] = a;
  }
}

extern "C" void kernel_launch(void* const* d_in, const int* in_sizes, int n_in,
                              void* d_out, int out_size, void* d_ws, size_t ws_size,
                              hipStream_t stream)
{
  (void)in_sizes; (void)n_in; (void)out_size; (void)ws_size;
  const float* x   = (const float*)d_in[0];
  const float* Wq  = (const float*)d_in[1];
  const float* bq  = (const float*)d_in[2];
  const float* Wkv = (const float*)d_in[3];
  const float* bkv = (const float*)d_in[4];
  const float* Wo  = (const float*)d_in[5];
  const float* bo  = (const float*)d_in[6];
  const float* W1  = (const float*)d_in[7];
  const float* b1  = (const float*)d_in[8];
  const float* W2  = (const float*)d_in[9];
  const float* b2  = (const float*)d_in[10];
  float* outp = (float*)d_out;
  float* ws = (float*)d_ws;
  float* ctx    = ws;                  // [8][16][768] = 98304
  float* denom  = ctx + 98304;         // [8][16]      = 128
  float* qv     = denom + 128;         // [8][768]     = 6144
  float* oat    = qv + 6144;           // [8][768]     = 6144
  float* lastb  = oat + 6144;          // [8][768]     = 6144
  float* hid    = lastb + 6144;        // [8][3072]    = 24576
  float* qWf    = hid + 24576;         // [8][16][768] = 98304

  hipMemsetAsync(ctx, 0, (size_t)(98304+128)*sizeof(float), stream);
  hipLaunchKernelGGL(k_q,    dim3(24,B_), dim3(256), 0, stream, x, Wq, bq, qv);
  hipLaunchKernelGGL(k_qw,   dim3(48,B_), dim3(256), 0, stream, qv, Wkv, qWf);
  hipLaunchKernelGGL(k_attn, dim3(64,B_), dim3(512), 0, stream, x, qWf, outp, ctx, denom);
  hipLaunchKernelGGL(k_v,    dim3(24,B_), dim3(256), 0, stream, ctx, denom, Wkv, bkv, oat);
  hipLaunchKernelGGL(k_o,    dim3(24,B_), dim3(256), 0, stream, x, oat, Wo, bo, lastb);
  hipLaunchKernelGGL(k_mlp1, dim3(192), dim3(256), 0, stream, lastb, W1, b1, hid);
  hipLaunchKernelGGL(k_mlp2, dim3(96), dim3(256), 0, stream, hid, W2, b2, lastb, outp);
}